// Round 3
// baseline (860.219 us; speedup 1.0000x reference)
//
#include <hip/hip_runtime.h>
#include <hip/hip_bf16.h>

// Problem constants (fixed by setup_inputs)
#define BB 4
#define HH 12
#define PP 1568
#define TT 8
#define DD 196          // PP / FRAME_T
#define HD 64
#define NUMK 10
#define NBH (BB*HH)     // 48
#define NBLK (NBH*PP)   // 75264
#define NEG_INF (-3.0e38f)

typedef unsigned long long ull;

__device__ __forceinline__ float readlane_f(float v, int l) {
    return __int_as_float(__builtin_amdgcn_readlane(__float_as_int(v), l));
}

// wave-wide sum, uniform result.
__device__ __forceinline__ float wave_sum_u(float v) {
#define STEPS(ctrl) { float t_ = __int_as_float(__builtin_amdgcn_update_dpp( \
        0, __float_as_int(v), ctrl, 0xF, 0xF, true)); v += t_; }
    STEPS(0x111) STEPS(0x112) STEPS(0x114) STEPS(0x118) STEPS(0x142) STEPS(0x143)
#undef STEPS
    return readlane_f(v, 63);
}

// Monotone float<->u32 order-preserving transform (all-SALU on uniform values).
__device__ __forceinline__ float untrans(unsigned v) {
    unsigned u = (v & 0x80000000u) ? (v ^ 0x80000000u) : ~v;
    return __uint_as_float(u);
}

#define T_LO 0x3E0FFFFFu   // t(-30.0f)
#define T_HI 0xC1F00000u   // t(+30.0f)
#define T_P0 0xC0400000u   // t(3.0f)  scripted probe 0
#define T_P1 0xBF800000u   // t(1.0f)  scripted probe 1

// Bisection state for one row (all wave-uniform -> SGPRs).
struct BiState {
    unsigned lo, hi, tau;
    bool done, needEpi;
    ull m0, m1, m2, m3;
};

__device__ __forceinline__ void bi_step(BiState& st, const float4& a, int it) {
    if (st.done) return;
    unsigned mid;
    if (it == 0)      mid = T_P0;
    else if (it == 1) mid = T_P1;
    else              mid = st.lo + ((st.hi - st.lo) >> 1);
    // clamp scripted probes into (lo, hi)
    unsigned lo1 = st.lo + 1, hi1 = st.hi - 1;
    mid = (mid < lo1) ? lo1 : (mid > hi1) ? hi1 : mid;
    float tf = untrans(mid);
    ull c0 = __ballot(a.x >= tf);
    ull c1 = __ballot(a.y >= tf);
    ull c2 = __ballot(a.z >= tf);
    ull c3 = __ballot(a.w >= tf);
    int cnt = __popcll(c0) + __popcll(c1) + __popcll(c2) + __popcll(c3);
    cnt = __builtin_amdgcn_readfirstlane(cnt);
    if (cnt == NUMK) {
        st.tau = mid; st.done = true; st.needEpi = false;
        st.m0 = c0; st.m1 = c1; st.m2 = c2; st.m3 = c3;
    } else {
        if (cnt > NUMK) st.lo = mid; else st.hi = mid;
        if (st.hi - st.lo <= 1) {      // collapse: tie at the margin
            st.tau = st.lo; st.done = true; st.needEpi = true;
        }
    }
}

__device__ __forceinline__ void bi_finish(BiState& st, const float4& a) {
    if (st.needEpi) {   // recompute kept masks at final tau (rare path)
        float tf = untrans(st.tau);
        st.m0 = __ballot(a.x >= tf);
        st.m1 = __ballot(a.y >= tf);
        st.m2 = __ballot(a.z >= tf);
        st.m3 = __ballot(a.w >= tf);
    }
}

// Weighted gather: o[lane] = sum_d w_d * v[(4l+j)*8+t][lane] / sum w_d.
__device__ __forceinline__ float gather_rows(const BiState& st, const float4& w,
        const float* __restrict__ vbt, int lane) {
    float o = 0.f, wsum = 0.f;
#pragma unroll
    for (int j = 0; j < 4; ++j) {
        ull   mm = (j==0)?st.m0:(j==1)?st.m1:(j==2)?st.m2:st.m3;
        float ws = (j==0)?w.x:(j==1)?w.y:(j==2)?w.z:w.w;
        while (mm) {   // wave-uniform loop
            int l0 = __ffsll(mm) - 1; mm &= mm - 1;
            float wa = readlane_f(ws, l0);
            const float* r0 = vbt + (size_t)(4*l0 + j) * (TT * HD);
            if (mm) {  // keep two loads in flight
                int l1 = __ffsll(mm) - 1; mm &= mm - 1;
                float wb = readlane_f(ws, l1);
                const float* r1 = vbt + (size_t)(4*l1 + j) * (TT * HD);
                float va = r0[lane];
                float vb = r1[lane];
                o = fmaf(wa, va, o); wsum += wa;
                o = fmaf(wb, vb, o); wsum += wb;
            } else {
                o = fmaf(wa, r0[lane], o); wsum += wa;
            }
        }
    }
    return o * __builtin_amdgcn_rcpf(wsum);
}

__device__ __forceinline__ float4 make_w(const BiState& st, const float4& a) {
    float tf = untrans(st.tau);
    float4 w;
    w.x = __expf(a.x - tf);
    w.y = __expf(a.y - tf);
    w.z = __expf(a.z - tf);
    w.w = __expf(a.w - tf);
    return w;
}

// Process the s-row and t-row for one (bh,p,t): bisection for both rows in
// one wave-uniform loop (scalar-pipe bracket updates), then gather.
__device__ __forceinline__ void process_pair(
        const float* __restrict__ rowS, const float* __restrict__ rowT,
        const float* __restrict__ vbtS, const float* __restrict__ vbtT,
        int lane, float& osR, float& otR)
{
    // lane l<49 holds elements 4l..4l+3 (196 = 49*4 exactly)
    float4 a, b;
    if (lane < 49) {
        a = *(const float4*)(rowS + 4*lane);
        b = *(const float4*)(rowT + 4*lane);
    } else {
        a.x = a.y = a.z = a.w = NEG_INF;
        b.x = b.y = b.z = b.w = NEG_INF;
    }

    BiState S, T;
    S.lo = T_LO; S.hi = T_HI; S.done = false; S.needEpi = true; S.tau = T_LO;
    T.lo = T_LO; T.hi = T_HI; T.done = false; T.needEpi = true; T.tau = T_LO;

    for (int it = 0; it < 40 && !(S.done && T.done); ++it) {
        bi_step(S, a, it);
        bi_step(T, b, it);
    }
    bi_finish(S, a);
    bi_finish(T, b);

    float4 wS = make_w(S, a);
    float4 wT = make_w(T, b);

    osR = gather_rows(S, wS, vbtS, lane);
    otR = gather_rows(T, wT, vbtT, lane);
}

__global__ __launch_bounds__(256, 8) void vtop_main(
        const float* __restrict__ att_s, const float* __restrict__ att_t,
        const float* __restrict__ v_s,   const float* __restrict__ v_t,
        float* __restrict__ partial) {
    int bid  = blockIdx.x;
    int p    = bid % PP;
    int bh   = bid / PP;
    int lane = threadIdx.x & 63;
    int wid  = threadIdx.x >> 6;

    size_t rowbase = ((size_t)bh * PP + p) * PP;
    const float* rs = att_s + rowbase;
    const float* rt = att_t + rowbase;
    size_t vbase = (size_t)bh * PP * HD;

    float acc = 0.f;
#pragma unroll
    for (int tt = 0; tt < 2; ++tt) {
        int t = wid * 2 + tt;
        float os, ot;
        process_pair(rs + t * DD, rt + t * DD,
                     v_s + vbase + t * HD, v_t + vbase + t * HD,
                     lane, os, ot);
        float d = os - ot;
        acc = fmaf(d, d, acc);
    }

    float wtot = wave_sum_u(acc);
    __shared__ float sm[4];
    if (lane == 0) sm[wid] = wtot;
    __syncthreads();
    if (threadIdx.x == 0) {
        partial[bid] = sm[0] + sm[1] + sm[2] + sm[3];
    }
}

__global__ __launch_bounds__(256) void vtop_reduce(
        const float* __restrict__ partial, float* __restrict__ out) {
    __shared__ double smd[256];
    double a = 0.0;
    for (int i = threadIdx.x; i < NBLK; i += 256) a += (double)partial[i];
    smd[threadIdx.x] = a;
    __syncthreads();
    for (int s = 128; s > 0; s >>= 1) {
        if (threadIdx.x < s) smd[threadIdx.x] += smd[threadIdx.x + s];
        __syncthreads();
    }
    if (threadIdx.x == 0) {
        const double inv_n = 1.0 / ((double)NBH * PP * TT * HD);  // 1/38535168
        out[0] = (float)(smd[0] * inv_n);
    }
}

extern "C" void kernel_launch(void* const* d_in, const int* in_sizes, int n_in,
                              void* d_out, int out_size, void* d_ws, size_t ws_size,
                              hipStream_t stream) {
    const float* att_s = (const float*)d_in[0];
    const float* att_t = (const float*)d_in[1];
    const float* v_s   = (const float*)d_in[2];
    const float* v_t   = (const float*)d_in[3];
    float* out     = (float*)d_out;
    float* partial = (float*)d_ws;   // NBLK floats = 301 KB

    vtop_main<<<NBLK, 256, 0, stream>>>(att_s, att_t, v_s, v_t, partial);
    vtop_reduce<<<1, 256, 0, stream>>>(partial, out);
}